// Round 12
// baseline (78.918 us; speedup 1.0000x reference)
//
#include <hip/hip_runtime.h>
#include <cmath>

#define HID 1024
#define OUTN 512
#define VOCABN 1024
#define MSIZE 262144
#define MDIM 128

// workspace layout (floats)
#define WS_H   0      // [1024] h
#define WS_AW  1024   // [2]    softmax action weights
#define WS_NE  1040   // [128]  new_elt (1040*4=4160, 16B aligned)

__device__ __forceinline__ float wred(float v) {
#pragma unroll
    for (int m = 32; m; m >>= 1) v += __shfl_xor(v, m, 64);
    return v;
}

// wave-cooperative dot over n4 float4s (result in all lanes)
__device__ __forceinline__ float dot4(const float4* __restrict__ a,
                                      const float4* __restrict__ b,
                                      int n4, int lane) {
    float acc = 0.f;
    for (int k = lane; k < n4; k += 64) {
        float4 x = a[k], y = b[k];
        acc = fmaf(x.x, y.x, fmaf(x.y, y.y, fmaf(x.z, y.z, fmaf(x.w, y.w, acc))));
    }
    return wred(acc);
}

__device__ __forceinline__ float4 blend4(float aw0, float aw1, float4 push, float4 pop) {
    float4 r;
    r.x = fmaf(aw0, push.x, aw1 * pop.x);
    r.y = fmaf(aw0, push.y, aw1 * pop.y);
    r.z = fmaf(aw0, push.z, aw1 * pop.z);
    r.w = fmaf(aw0, push.w, aw1 * pop.w);
    return r;
}

// Kernel 1 (fused): per-block redundant hidden_bar (lane-parallel over rows,
// NO shuffles -- this is what made R2/R6's fusion slow), then h = tanh(...).
// 128 blocks x 512 threads; 8 h-rows per block (1 wave per row).
__global__ __launch_bounds__(512) void k_fused(
    const float* __restrict__ stack, const float* __restrict__ hidden0,
    const float* __restrict__ input, const float* __restrict__ W_sh,
    const float* __restrict__ b_sh, const float* __restrict__ W_ih,
    const float* __restrict__ W_hh, const float* __restrict__ b_ih,
    const float* __restrict__ b_hh, float* __restrict__ ws,
    float* __restrict__ d_out) {
    __shared__ __align__(16) float s0[MDIM];
    __shared__ __align__(16) float hb[HID];
    const int t = threadIdx.x;

    // stage stack row 0
    if (t < 32) ((float4*)s0)[t] = ((const float4*)stack)[t];
    __syncthreads();

    // phase 1: hb[j] = W_sh[j,:]·s0 + b_sh[j] + hidden0[j]; thread t does
    // rows t and t+512. W_sh row reads are per-thread-sequential (L1-temporal,
    // W_sh is 512KB and L2-resident); s0 reads broadcast from LDS.
    const float4* s04 = (const float4*)s0;
    for (int j = t; j < HID; j += 512) {
        const float4* w = (const float4*)(W_sh + j * MDIM);
        float acc = 0.f;
#pragma unroll 8
        for (int k = 0; k < MDIM / 4; ++k) {
            const float4 a = w[k], s = s04[k];
            acc = fmaf(a.x, s.x, fmaf(a.y, s.y, fmaf(a.z, s.z, fmaf(a.w, s.w, acc))));
        }
        hb[j] = acc + b_sh[j] + hidden0[j];
    }
    __syncthreads();

    // phase 2: h[R] = tanh(W_ih[R]·input + W_hh[R]·hb + b_ih[R] + b_hh[R])
    const int lane = t & 63;
    const int R = blockIdx.x * 8 + (t >> 6);
    const float4* wi  = (const float4*)(W_ih + R * VOCABN);
    const float4* wh  = (const float4*)(W_hh + R * HID);
    const float4* in4 = (const float4*)input;
    const float4* hb4 = (const float4*)hb;
    float acc = 0.f;
    for (int k = lane; k < VOCABN / 4; k += 64) {
        float4 a = wi[k], b = in4[k];
        acc = fmaf(a.x, b.x, fmaf(a.y, b.y, fmaf(a.z, b.z, fmaf(a.w, b.w, acc))));
        float4 c = wh[k], d = hb4[k];
        acc = fmaf(c.x, d.x, fmaf(c.y, d.y, fmaf(c.z, d.z, fmaf(c.w, d.w, acc))));
    }
    acc = wred(acc);
    if (lane == 0) {
        const float h = tanhf(acc + b_ih[R] + b_hh[R]);
        ws[WS_H + R] = h;
        d_out[OUTN + R] = h;
    }
}

// Kernel 2: output (512), new_elt (128), action softmax (1 wave) -- R11-exact
__global__ void k_heads(const float* __restrict__ W_y, const float* __restrict__ b_y,
                        const float* __restrict__ W_n, const float* __restrict__ b_n,
                        const float* __restrict__ W_a, const float* __restrict__ b_a,
                        float* __restrict__ ws, float* __restrict__ d_out) {
    const int lane = threadIdx.x & 63;
    const int row = blockIdx.x * (blockDim.x >> 6) + (threadIdx.x >> 6);
    const float4* h4 = (const float4*)(ws + WS_H);
    if (row < OUTN) {
        float a = dot4((const float4*)(W_y + row * HID), h4, HID / 4, lane);
        if (lane == 0) d_out[row] = 1.f / (1.f + expf(-(a + b_y[row])));
    } else if (row < OUTN + MDIM) {
        const int m = row - OUTN;
        float a = dot4((const float4*)(W_n + m * HID), h4, HID / 4, lane);
        if (lane == 0) ws[WS_NE + m] = 1.f / (1.f + expf(-(a + b_n[m])));
    } else if (row == OUTN + MDIM) {
        float l0 = dot4((const float4*)(W_a), h4, HID / 4, lane);
        float l1 = dot4((const float4*)(W_a + HID), h4, HID / 4, lane);
        if (lane == 0) {
            l0 += b_a[0];
            l1 += b_a[1];
            const float mx = fmaxf(l0, l1);
            const float e0 = expf(l0 - mx), e1 = expf(l1 - mx);
            const float s = e0 + e1;
            ws[WS_AW]     = e0 / s;
            ws[WS_AW + 1] = e1 / s;
        }
    }
}

// Kernel 3: sliding-window blend -- R11-exact.
__global__ __launch_bounds__(256, 8) void k_stack(
    const float* __restrict__ stack, const float* __restrict__ ws,
    float* __restrict__ out_stack) {
    const float aw0 = ws[WS_AW];
    const float aw1 = ws[WS_AW + 1];
    const float4* s4  = (const float4*)stack;
    const float4* ne4 = (const float4*)(ws + WS_NE);
    float4* o4 = (float4*)out_stack;
    const int total4 = MSIZE * (MDIM / 4);              // 8,388,608
    const int lane = threadIdx.x & 63;
    const int wid  = blockIdx.x * 4 + (threadIdx.x >> 6);  // 0..8191
    const long base = (long)wid * 1024;

    float4 prev;
    if (wid == 0) prev = (lane < 32) ? ne4[lane] : s4[lane - 32];
    else          prev = s4[base - 32 + lane];

#pragma unroll 4
    for (int i = 0; i < 16; ++i) {
        const long A = base + i * 64;
        const long nidx = A + 32 + lane;
        float4 next = make_float4(0.f, 0.f, 0.f, 0.f);
        if (nidx < total4) next = s4[nidx];
        o4[A + lane] = blend4(aw0, aw1, prev, next);
        prev = next;
    }
}

extern "C" void kernel_launch(void* const* d_in, const int* in_sizes, int n_in,
                              void* d_out, int out_size, void* d_ws, size_t ws_size,
                              hipStream_t stream) {
    const float* input   = (const float*)d_in[0];
    const float* hidden0 = (const float*)d_in[1];
    const float* stack   = (const float*)d_in[2];
    const float* W_ih    = (const float*)d_in[3];
    const float* W_hh    = (const float*)d_in[4];
    const float* b_ih    = (const float*)d_in[5];
    const float* b_hh    = (const float*)d_in[6];
    const float* W_y     = (const float*)d_in[7];
    const float* b_y     = (const float*)d_in[8];
    const float* W_n     = (const float*)d_in[9];
    const float* b_n     = (const float*)d_in[10];
    const float* W_a     = (const float*)d_in[11];
    const float* b_a     = (const float*)d_in[12];
    const float* W_sh    = (const float*)d_in[13];
    const float* b_sh    = (const float*)d_in[14];
    float* out = (float*)d_out;
    float* ws  = (float*)d_ws;

    k_fused<<<128, 512, 0, stream>>>(stack, hidden0, input, W_sh, b_sh,
                                     W_ih, W_hh, b_ih, b_hh, ws, out);
    k_heads<<<161, 256, 0, stream>>>(W_y, b_y, W_n, b_n, W_a, b_a, ws, out);
    k_stack<<<2048, 256, 0, stream>>>(stack, ws, out + OUTN + HID);
}

// Round 13
// 60.095 us; speedup vs baseline: 1.3132x; 1.3132x over previous
//
#include <hip/hip_runtime.h>
#include <cmath>

#define HID 1024
#define OUTN 512
#define VOCABN 1024
#define MSIZE 262144
#define MDIM 128

// workspace layout (floats)
#define WS_TIH 0      // [1024] W_ih@input + b_ih
#define WS_HB  1024   // [1024] hidden_bar
#define WS_H   2048   // [1024] h
#define WS_AW  3072   // [2]    softmax action weights
#define WS_NE  3076   // [128]  new_elt (16B aligned)

typedef float f4_t __attribute__((ext_vector_type(4)));

__device__ __forceinline__ float wred(float v) {
#pragma unroll
    for (int m = 32; m; m >>= 1) v += __shfl_xor(v, m, 64);
    return v;
}

// wave-cooperative dot over n4 float4s (result in all lanes)
__device__ __forceinline__ float dot4(const float4* __restrict__ a,
                                      const float4* __restrict__ b,
                                      int n4, int lane) {
    float acc = 0.f;
    for (int k = lane; k < n4; k += 64) {
        float4 x = a[k], y = b[k];
        acc = fmaf(x.x, y.x, fmaf(x.y, y.y, fmaf(x.z, y.z, fmaf(x.w, y.w, acc))));
    }
    return wred(acc);
}

// Kernel A: t_ih[row] = W_ih[row,:]·input + b_ih[row]
//           hidden_bar[row] = W_sh[row,:]·stack[0,:] + b_sh[row] + hidden0[row]
__global__ void k_pre(const float* __restrict__ input, const float* __restrict__ hidden0,
                      const float* __restrict__ stack, const float* __restrict__ W_ih,
                      const float* __restrict__ b_ih, const float* __restrict__ W_sh,
                      const float* __restrict__ b_sh, float* __restrict__ ws) {
    const int lane = threadIdx.x & 63;
    const int row = blockIdx.x * (blockDim.x >> 6) + (threadIdx.x >> 6);
    if (row >= HID) return;
    float t  = dot4((const float4*)(W_ih + row * VOCABN), (const float4*)input, VOCABN / 4, lane);
    float hb = dot4((const float4*)(W_sh + row * MDIM), (const float4*)stack, MDIM / 4, lane);
    if (lane == 0) {
        ws[WS_TIH + row] = t + b_ih[row];
        ws[WS_HB + row]  = hb + b_sh[row] + hidden0[row];
    }
}

// Kernel B: h[row] = tanh(t_ih[row] + W_hh[row,:]·hidden_bar + b_hh[row])
__global__ void k_h(const float* __restrict__ W_hh, const float* __restrict__ b_hh,
                    float* __restrict__ ws, float* __restrict__ d_out) {
    const int lane = threadIdx.x & 63;
    const int row = blockIdx.x * (blockDim.x >> 6) + (threadIdx.x >> 6);
    if (row >= HID) return;
    float a = dot4((const float4*)(W_hh + row * HID), (const float4*)(ws + WS_HB), HID / 4, lane);
    if (lane == 0) {
        float h = tanhf(ws[WS_TIH + row] + a + b_hh[row]);
        ws[WS_H + row] = h;
        d_out[OUTN + row] = h;
    }
}

// Kernel C: output (512), new_elt (128), action softmax (1 wave)
__global__ void k_heads(const float* __restrict__ W_y, const float* __restrict__ b_y,
                        const float* __restrict__ W_n, const float* __restrict__ b_n,
                        const float* __restrict__ W_a, const float* __restrict__ b_a,
                        float* __restrict__ ws, float* __restrict__ d_out) {
    const int lane = threadIdx.x & 63;
    const int row = blockIdx.x * (blockDim.x >> 6) + (threadIdx.x >> 6);
    const float4* h4 = (const float4*)(ws + WS_H);
    if (row < OUTN) {
        float a = dot4((const float4*)(W_y + row * HID), h4, HID / 4, lane);
        if (lane == 0) d_out[row] = 1.f / (1.f + expf(-(a + b_y[row])));
    } else if (row < OUTN + MDIM) {
        const int m = row - OUTN;
        float a = dot4((const float4*)(W_n + m * HID), h4, HID / 4, lane);
        if (lane == 0) ws[WS_NE + m] = 1.f / (1.f + expf(-(a + b_n[m])));
    } else if (row == OUTN + MDIM) {
        float l0 = dot4((const float4*)(W_a), h4, HID / 4, lane);
        float l1 = dot4((const float4*)(W_a + HID), h4, HID / 4, lane);
        if (lane == 0) {
            l0 += b_a[0];
            l1 += b_a[1];
            const float mx = fmaxf(l0, l1);
            const float e0 = expf(l0 - mx), e1 = expf(l1 - mx);
            const float s = e0 + e1;
            ws[WS_AW]     = e0 / s;
            ws[WS_AW + 1] = e1 / s;
        }
    }
}

// Kernel D: sliding-window blend (R11-exact) + NONTEMPORAL stores.
// NT stores are no-allocate in the cache hierarchy -> the 128MB output no
// longer evicts the 128MB stack from the 256MB LLC -> next replay's stack
// reads become LLC hits (FETCH_SIZE should drop from ~70MB toward ~10MB).
__global__ __launch_bounds__(256, 8) void k_stack(
    const float* __restrict__ stack, const float* __restrict__ ws,
    float* __restrict__ out_stack) {
    const float aw0 = ws[WS_AW];
    const float aw1 = ws[WS_AW + 1];
    const float4* s4  = (const float4*)stack;
    const float4* ne4 = (const float4*)(ws + WS_NE);
    f4_t* o4 = (f4_t*)out_stack;
    const int total4 = MSIZE * (MDIM / 4);              // 8,388,608
    const int lane = threadIdx.x & 63;
    const int wid  = blockIdx.x * 4 + (threadIdx.x >> 6);  // 0..8191
    const long base = (long)wid * 1024;

    float4 prev;
    if (wid == 0) prev = (lane < 32) ? ne4[lane] : s4[lane - 32];
    else          prev = s4[base - 32 + lane];

#pragma unroll 4
    for (int i = 0; i < 16; ++i) {
        const long A = base + i * 64;
        const long nidx = A + 32 + lane;
        float4 next = make_float4(0.f, 0.f, 0.f, 0.f);
        if (nidx < total4) next = s4[nidx];
        f4_t r;
        r.x = fmaf(aw0, prev.x, aw1 * next.x);
        r.y = fmaf(aw0, prev.y, aw1 * next.y);
        r.z = fmaf(aw0, prev.z, aw1 * next.z);
        r.w = fmaf(aw0, prev.w, aw1 * next.w);
        __builtin_nontemporal_store(r, &o4[A + lane]);
        prev = next;
    }
}

extern "C" void kernel_launch(void* const* d_in, const int* in_sizes, int n_in,
                              void* d_out, int out_size, void* d_ws, size_t ws_size,
                              hipStream_t stream) {
    const float* input   = (const float*)d_in[0];
    const float* hidden0 = (const float*)d_in[1];
    const float* stack   = (const float*)d_in[2];
    const float* W_ih    = (const float*)d_in[3];
    const float* W_hh    = (const float*)d_in[4];
    const float* b_ih    = (const float*)d_in[5];
    const float* b_hh    = (const float*)d_in[6];
    const float* W_y     = (const float*)d_in[7];
    const float* b_y     = (const float*)d_in[8];
    const float* W_n     = (const float*)d_in[9];
    const float* b_n     = (const float*)d_in[10];
    const float* W_a     = (const float*)d_in[11];
    const float* b_a     = (const float*)d_in[12];
    const float* W_sh    = (const float*)d_in[13];
    const float* b_sh    = (const float*)d_in[14];
    float* out = (float*)d_out;
    float* ws  = (float*)d_ws;

    // A: 1024 rows, 4 waves/block -> 256 blocks
    k_pre<<<256, 256, 0, stream>>>(input, hidden0, stack, W_ih, b_ih, W_sh, b_sh, ws);
    // B: 1024 rows
    k_h<<<256, 256, 0, stream>>>(W_hh, b_hh, ws, out);
    // C: 641 rows
    k_heads<<<161, 256, 0, stream>>>(W_y, b_y, W_n, b_n, W_a, b_a, ws, out);
    // D: sliding-window blend + NT stores
    k_stack<<<2048, 256, 0, stream>>>(stack, ws, out + OUTN + HID);
}